// Round 16
// baseline (562.773 us; speedup 1.0000x reference)
//
#include <hip/hip_runtime.h>
#include <cstdint>
#include <cstddef>

typedef __attribute__((ext_vector_type(4))) float  f32x4;
typedef __attribute__((ext_vector_type(8))) __bf16 bf16x8;
typedef __attribute__((ext_vector_type(4))) __bf16 bf16x4;

#define MFMA16(A, B, C) __builtin_amdgcn_mfma_f32_16x16x32_bf16((A), (B), (C), 0, 0, 0)

// async global->LDS, 16B per lane, wave-uniform LDS base + lane*16
#define GLOAD_LDS16(gp, lp)                                        \
    __builtin_amdgcn_global_load_lds(                              \
        (const __attribute__((address_space(1))) void*)(gp),       \
        (__attribute__((address_space(3))) void*)(lp), 16, 0, 0)

// problem constants
#define NB 256
#define NN 198
#define NC 768
#define NH 12

// ---------------------------------------------------------------------------
// Merged prep: blocks [0,2048) grid-stride cast x f32->bf16 (16B/lane);
// blocks [2048,3776) transpose w_qkv; blocks [3776,4352) transpose w_proj.
// ---------------------------------------------------------------------------
__global__ __launch_bounds__(256) void prep_kernel(
    const float* __restrict__ x, __bf16* __restrict__ xb,
    const float* __restrict__ w_qkv, __bf16* __restrict__ wqkvT,
    const float* __restrict__ w_proj, __bf16* __restrict__ wprojT) {
    __shared__ __bf16 tile[32][33];
    const int blk = blockIdx.x;
    if (blk < 2048) {
        const int n8 = 50688 * 768 / 8;
        for (int i = blk * 256 + threadIdx.x; i < n8; i += 2048 * 256) {
            const float4 f0 = reinterpret_cast<const float4*>(x)[i * 2];
            const float4 f1 = reinterpret_cast<const float4*>(x)[i * 2 + 1];
            bf16x8 h;
            h[0] = (__bf16)f0.x; h[1] = (__bf16)f0.y; h[2] = (__bf16)f0.z; h[3] = (__bf16)f0.w;
            h[4] = (__bf16)f1.x; h[5] = (__bf16)f1.y; h[6] = (__bf16)f1.z; h[7] = (__bf16)f1.w;
            reinterpret_cast<bf16x8*>(xb)[i] = h;
        }
    } else {
        int tb = blk - 2048;
        const float* in;
        __bf16* outp_;
        int R, Cc;
        if (tb < 1728) { in = w_qkv; outp_ = wqkvT; R = 768; Cc = 2304; }
        else           { tb -= 1728; in = w_proj; outp_ = wprojT; R = 768; Cc = 768; }
        const int ntc = Cc >> 5;
        const int tc = tb % ntc, tr = tb / ntc;
        const int c0 = tc * 32, r0 = tr * 32;
        const int lx = threadIdx.x & 31, ly = threadIdx.x >> 5;   // 32 x 8
#pragma unroll
        for (int j = 0; j < 4; ++j)
            tile[ly + j * 8][lx] = (__bf16)in[(size_t)(r0 + ly + j * 8) * Cc + c0 + lx];
        __syncthreads();
#pragma unroll
        for (int j = 0; j < 4; ++j)
            outp_[(size_t)(c0 + ly + j * 8) * R + r0 + lx] = tile[lx][ly + j * 8];
    }
}

// ---------------------------------------------------------------------------
// GEMM v7 (best measured, reproduced r10/r12/r13/r15: ~260us, MfmaUtil ~30%):
// 256x256, 8 waves, BK=64 dbuf, counted vmcnt(8), 4-phase intra-iter
// pipeline with counted lgkmcnt.
// ---------------------------------------------------------------------------
__global__ __launch_bounds__(512, 2) void gemm_qkv_v7(
    const __bf16* __restrict__ xb, const __bf16* __restrict__ wT,
    __bf16* __restrict__ qb, __bf16* __restrict__ kb, __bf16* __restrict__ vb,
    float* __restrict__ q0) {
    __shared__ __bf16 As[2][256 * 64];
    __shared__ __bf16 Bs[2][256 * 64];
    const int bid = blockIdx.x;
    const int xcd = bid & 7, lin = bid >> 3;
    const int wgid = (xcd < 6 ? xcd * 223 : 6 * 223 + (xcd - 6) * 222) + lin;
    const int brow = (wgid / 9) * 256;
    const int bcol = (wgid % 9) * 256;
    const int tid = threadIdx.x, lane = tid & 63, wid = tid >> 6;
    const int wr = wid >> 2, wc = wid & 3;
    const int lr = lane & 15, lg = lane >> 4;

    const int srow = tid >> 3;
    const int sslot = (tid & 7) ^ ((tid >> 3) & 7);
    const __bf16* aSrc = xb + (size_t)(brow + srow) * 768 + sslot * 8;
    const __bf16* bSrc = wT + (size_t)(bcol + srow) * 768 + sslot * 8;
    const int key = lr & 7;

    f32x4 acc[8][4] = {};

#define STAGE7(buf, kk0)                                                       \
    {                                                                          \
        __bf16* aD = &As[buf][wid * 512];                                      \
        __bf16* bD = &Bs[buf][wid * 512];                                      \
        _Pragma("unroll")                                                      \
        for (int j = 0; j < 4; ++j) {                                          \
            GLOAD_LDS16(aSrc + (size_t)j * 64 * 768 + (kk0), aD + j * 4096);   \
            GLOAD_LDS16(bSrc + (size_t)j * 64 * 768 + (kk0), bD + j * 4096);   \
        }                                                                      \
    }

#define LDA7(f0, f1, f2, f3, m0)                                               \
    f0 = *reinterpret_cast<const bf16x8*>(                                     \
        Ab + (wr * 128 + (m0) * 16 + lr) * 64 + ((lg ^ key) * 8));             \
    f1 = *reinterpret_cast<const bf16x8*>(                                     \
        Ab + (wr * 128 + (m0) * 16 + lr) * 64 + (((4 + lg) ^ key) * 8));       \
    f2 = *reinterpret_cast<const bf16x8*>(                                     \
        Ab + (wr * 128 + (m0) * 16 + 16 + lr) * 64 + ((lg ^ key) * 8));        \
    f3 = *reinterpret_cast<const bf16x8*>(                                     \
        Ab + (wr * 128 + (m0) * 16 + 16 + lr) * 64 + (((4 + lg) ^ key) * 8));

#define MFMA_PHASE7(f0, f1, f2, f3, m0)                                        \
    __builtin_amdgcn_s_setprio(1);                                             \
    _Pragma("unroll")                                                          \
    for (int nt = 0; nt < 4; ++nt) acc[(m0)][nt]     = MFMA16(f0, bfr[0][nt], acc[(m0)][nt]);     \
    _Pragma("unroll")                                                          \
    for (int nt = 0; nt < 4; ++nt) acc[(m0)][nt]     = MFMA16(f1, bfr[1][nt], acc[(m0)][nt]);     \
    _Pragma("unroll")                                                          \
    for (int nt = 0; nt < 4; ++nt) acc[(m0) + 1][nt] = MFMA16(f2, bfr[0][nt], acc[(m0) + 1][nt]); \
    _Pragma("unroll")                                                          \
    for (int nt = 0; nt < 4; ++nt) acc[(m0) + 1][nt] = MFMA16(f3, bfr[1][nt], acc[(m0) + 1][nt]); \
    __builtin_amdgcn_s_setprio(0);

    STAGE7(0, 0);
    STAGE7(1, 64);
    for (int tau = 0; tau < 12; ++tau) {
        const int b = tau & 1;
        if (tau == 11) asm volatile("s_waitcnt vmcnt(0)" ::: "memory");
        else           asm volatile("s_waitcnt vmcnt(8)" ::: "memory");
        __builtin_amdgcn_s_barrier();
        __builtin_amdgcn_sched_barrier(0);
        const __bf16* Ab = As[b];
        const __bf16* Bb = Bs[b];
        bf16x8 bfr[2][4];
#pragma unroll
        for (int kk = 0; kk < 2; ++kk)
#pragma unroll
            for (int nt = 0; nt < 4; ++nt)
                bfr[kk][nt] = *reinterpret_cast<const bf16x8*>(
                    Bb + (wc * 64 + nt * 16 + lr) * 64 + (((kk * 4 + lg) ^ key) * 8));
        bf16x8 a0, a1, a2, a3, b0, b1, b2, b3;
        LDA7(a0, a1, a2, a3, 0);
        LDA7(b0, b1, b2, b3, 2);
        asm volatile("s_waitcnt lgkmcnt(4)" ::: "memory");
        __builtin_amdgcn_sched_barrier(0);
        MFMA_PHASE7(a0, a1, a2, a3, 0);
        LDA7(a0, a1, a2, a3, 4);
        asm volatile("s_waitcnt lgkmcnt(4)" ::: "memory");
        __builtin_amdgcn_sched_barrier(0);
        MFMA_PHASE7(b0, b1, b2, b3, 2);
        LDA7(b0, b1, b2, b3, 6);
        asm volatile("s_waitcnt lgkmcnt(4)" ::: "memory");
        __builtin_amdgcn_sched_barrier(0);
        MFMA_PHASE7(a0, a1, a2, a3, 4);
        asm volatile("s_waitcnt lgkmcnt(0)" ::: "memory");
        __builtin_amdgcn_sched_barrier(0);
        __builtin_amdgcn_s_barrier();
        __builtin_amdgcn_sched_barrier(0);
        if (tau < 10) STAGE7(b, (tau + 2) * 64);
        MFMA_PHASE7(b0, b1, b2, b3, 6);
    }
#undef STAGE7

    // epilogue: D layout row=(lane>>4)*4+reg, col=lane&15  [m89-verified]
#pragma unroll
    for (int mt = 0; mt < 8; ++mt) {
        int grow0 = brow + wr * 128 + mt * 16 + lg * 4;
        int bbs[4], nns[4];
#pragma unroll
        for (int r = 0; r < 4; ++r) {
            bbs[r] = (grow0 + r) / 198;
            nns[r] = (grow0 + r) % 198;
        }
#pragma unroll
        for (int nt = 0; nt < 4; ++nt) {
            int gcol = bcol + wc * 64 + nt * 16 + lr;   // 0..2303
            int sidx = gcol / 768;
            int rem  = gcol % 768;                      // h*64+d
            __bf16* dstbuf = (sidx == 0) ? qb : (sidx == 1) ? kb : vb;
            int hh = rem >> 6, dd = rem & 63;
#pragma unroll
            for (int r = 0; r < 4; ++r) {
                float val = acc[mt][nt][r];
                dstbuf[(((size_t)bbs[r] * 12 + hh) * 198 + nns[r]) * 64 + dd] = (__bf16)val;
                if (sidx == 0 && nns[r] == 0) q0[bbs[r] * 768 + rem] = val;
            }
        }
    }
}

// ---------------------------------------------------------------------------
// Per-batch head: D/cen sigmoid heads from q0, then mixture-of-gaussian mgb.
// ---------------------------------------------------------------------------
__global__ __launch_bounds__(256) void mgb_kernel(
    const float* __restrict__ q0, const float* __restrict__ wD,
    const float* __restrict__ bD, const float* __restrict__ wcen,
    const float* __restrict__ bcen, float* __restrict__ cen_out,
    float* __restrict__ mgb) {
    const int b = blockIdx.x, t = threadIdx.x;
    __shared__ float qs[768];
    __shared__ float red[256];
    __shared__ float vals[9];
    qs[t]       = q0[b * 768 + t];
    qs[t + 256] = q0[b * 768 + t + 256];
    qs[t + 512] = q0[b * 768 + t + 512];
    __syncthreads();
    for (int j = 0; j < 9; ++j) {
        float p;
        if (j < 3)
            p = qs[t] * wD[t * 3 + j] + qs[t + 256] * wD[(t + 256) * 3 + j] +
                qs[t + 512] * wD[(t + 512) * 3 + j];
        else {
            int c = j - 3;
            p = qs[t] * wcen[t * 6 + c] + qs[t + 256] * wcen[(t + 256) * 6 + c] +
                qs[t + 512] * wcen[(t + 512) * 6 + c];
        }
        red[t] = p;
        __syncthreads();
        for (int off = 128; off > 0; off >>= 1) {
            if (t < off) red[t] += red[t + off];
            __syncthreads();
        }
        if (t == 0) {
            float bias = (j < 3) ? bD[j] : bcen[j - 3];
            vals[j] = 1.f / (1.f + __expf(-(red[0] + bias)));
        }
        __syncthreads();
    }
    if (t < 6) cen_out[b * 6 + t] = vals[3 + t];

    float e3[3] = {0.f, 0.f, 0.f};
    if (t < 196) {
        float gx = 8.f + 16.f * (float)(t / 14);   // GRIDS x-major
        float gy = 8.f + 16.f * (float)(t % 14);
#pragma unroll
        for (int j = 0; j < 3; ++j) {
            float sig = 112.f * vals[j];
            float cx = vals[3 + 2 * j] * 223.f;
            float cy = vals[3 + 2 * j + 1] * 223.f;
            float dx = cx - gx, dy = cy - gy;
            e3[j] = __expf(-(dx * dx + dy * dy) / (2.f * sig * sig));
        }
    }
    float js[3];
    for (int j = 0; j < 3; ++j) {
        red[t] = e3[j];
        __syncthreads();
        for (int off = 128; off > 0; off >>= 1) {
            if (t < off) red[t] += red[t + off];
            __syncthreads();
        }
        js[j] = red[0];
        __syncthreads();
    }
    if (t < 196) {
        float m = (e3[0] / js[0] + e3[1] / js[1] + e3[2] / js[2]) * (1.f / 3.f);
        mgb[(size_t)b * 198 + 2 + t] = m;
    }
    if (t < 2) mgb[(size_t)b * 198 + t] = 1.f;
}

// ---------------------------------------------------------------------------
// Attention per (b,h) v11: v9 with the P LDS roundtrip replaced by in-wave
// shuffles (T12-style). P[lr][c] lives in lane (lr, (c%16)>>2) at sa[c>>4][c&3];
// PV A-frag pf[0..3]/[4..7] = sa[T][0..3] from lanes sA=lr+(lg&1)*32, sB=sA+16,
// T = 2ks+(lg>>1) (compile-time indices after unroll -> no scratch, rule 20).
// LDS = Klds 26624 + Vt 27648 = 54272B -> 3 blocks/CU (162816 <= 163840).
// NO forced launch_bounds min (r14's (256,3) caused VGPR-84 spill: WRITE_SIZE
// 164MB, MfmaUtil 0.6%); compiler keeps sa in regs at default.
// ---------------------------------------------------------------------------
__global__ __launch_bounds__(256) void attn_kernel(
    const __bf16* __restrict__ qb, const __bf16* __restrict__ kb,
    const __bf16* __restrict__ vb, float* __restrict__ p0,
    __bf16* __restrict__ outp) {
    __shared__ __bf16 Klds[208 * 64];     // rows 198..207 duplicate row 197
    __shared__ __bf16 Vt[64][216];
    const int bh = blockIdx.x;
    const int b = bh / 12, h = bh % 12;
    const __bf16* Qp = qb + (size_t)bh * NN * 64;
    const __bf16* Kp = kb + (size_t)bh * NN * 64;
    const __bf16* Vp = vb + (size_t)bh * NN * 64;
    const int tid = threadIdx.x, lane = tid & 63, wid = tid >> 6;
    const int lr = lane & 15, lg = lane >> 4;

    {
        const int rsub = wid * 8 + (lane >> 3);            // 0..31 within issue
        const int sl   = ((lane & 7) ^ ((lane >> 3) & 7)) * 8;
#pragma unroll
        for (int i = 0; i < 7; ++i) {
            if (i < 6 || wid < 2) {
                int row = i * 32 + rsub;
                int rowc = row < 198 ? row : 197;
                GLOAD_LDS16(Kp + (size_t)rowc * 64 + sl,
                            Klds + (size_t)i * 2048 + wid * 512);
            }
        }
    }

    for (int i = tid; i < 104 * 8; i += 256) {
        int key2 = (i >> 3) * 2, d0 = (i & 7) << 3;
        int kr0 = key2 < 198 ? key2 : 197;
        int kr1 = key2 + 1 < 198 ? key2 + 1 : 197;
        bf16x8 h0 = *reinterpret_cast<const bf16x8*>(Vp + kr0 * 64 + d0);
        bf16x8 h1 = *reinterpret_cast<const bf16x8*>(Vp + kr1 * 64 + d0);
#pragma unroll
        for (int j = 0; j < 8; ++j) {
            union { __bf16 hh[2]; unsigned u; } pk;
            pk.hh[0] = h0[j]; pk.hh[1] = h1[j];
            *reinterpret_cast<unsigned*>(&Vt[d0 + j][key2]) = pk.u;
        }
    }
    __syncthreads();   // drains vmcnt (K stage) + lgkm (V writes)

    for (int ch = wid; ch < 13; ch += 4) {
        int n0 = ch * 16;
        int qrow = n0 + lr; if (qrow > 197) qrow = 197;
        bf16x8 qf0 = *reinterpret_cast<const bf16x8*>(Qp + qrow * 64 + lg * 8);
        bf16x8 qf1 = *reinterpret_cast<const bf16x8*>(Qp + qrow * 64 + 32 + lg * 8);
        f32x4 sa[13];
#pragma unroll
        for (int t2 = 0; t2 < 13; ++t2) {
            int krow = t2 * 16 + lr;                       // <= 207, in Klds
            const int kx = lr & 7;                         // krow & 7
            bf16x8 kf0 = *reinterpret_cast<const bf16x8*>(
                Klds + krow * 64 + ((lg ^ kx) * 8));
            bf16x8 kf1 = *reinterpret_cast<const bf16x8*>(
                Klds + krow * 64 + (((4 + lg) ^ kx) * 8));
            f32x4 a = (f32x4){0.f, 0.f, 0.f, 0.f};
            a = MFMA16(kf0, qf0, a);
            a = MFMA16(kf1, qf1, a);
            sa[t2] = a;
        }
        float rmax = -1e30f;
#pragma unroll
        for (int t2 = 0; t2 < 13; ++t2)
#pragma unroll
            for (int r = 0; r < 4; ++r) {
                int key = t2 * 16 + lg * 4 + r;
                float vv = (key < 198) ? sa[t2][r] * 0.125f : -1e30f;
                sa[t2][r] = vv;
                rmax = fmaxf(rmax, vv);
            }
        rmax = fmaxf(rmax, __shfl_xor(rmax, 16));
        rmax = fmaxf(rmax, __shfl_xor(rmax, 32));
        float rsum = 0.f;
#pragma unroll
        for (int t2 = 0; t2 < 13; ++t2)
#pragma unroll
            for (int r = 0; r < 4; ++r) {
                float e = __expf(sa[t2][r] - rmax);
                sa[t2][r] = e;
                rsum += e;
            }
        rsum += __shfl_xor(rsum, 16);
        rsum += __shfl_xor(rsum, 32);
        float inv = 1.f / rsum;

        if (ch == 0 && lr == 0) {
#pragma unroll
            for (int t2 = 0; t2 < 13; ++t2)
#pragma unroll
                for (int r = 0; r < 4; ++r) {
                    int key = t2 * 16 + lg * 4 + r;
                    if (key < 198) p0[(size_t)bh * 198 + key] = sa[t2][r] * inv;
                }
        }

        // pack P*inv into bf16 dword pairs (register-resident, static indices)
        unsigned pkA[13], pkB[13];
#pragma unroll
        for (int t2 = 0; t2 < 13; ++t2) {
            bf16x4 tmp;
#pragma unroll
            for (int r = 0; r < 4; ++r) tmp[r] = (__bf16)(sa[t2][r] * inv);
            union { bf16x4 v; unsigned u[2]; } cvt;
            cvt.v = tmp;
            pkA[t2] = cvt.u[0];
            pkB[t2] = cvt.u[1];
        }

        const int sA = lr + ((lane >> 4) & 1) * 32;   // lr + (lg&1)*32
        const int sB = sA + 16;
        const bool hiT = ((lane >> 5) & 1) != 0;      // lg>>1

        f32x4 o[4];
#pragma unroll
        for (int mt = 0; mt < 4; ++mt) o[mt] = (f32x4){0.f, 0.f, 0.f, 0.f};
#pragma unroll
        for (int ks = 0; ks < 7; ++ks) {
            const int kbase = ks * 32 + lg * 8;
            unsigned a00 = __shfl(pkA[2 * ks], sA);
            unsigned a01 = __shfl(pkB[2 * ks], sA);
            unsigned b00 = __shfl(pkA[2 * ks], sB);
            unsigned b01 = __shfl(pkB[2 * ks], sB);
            unsigned w0, w1, w2, w3;
            if (ks < 6) {
                unsigned a10 = __shfl(pkA[2 * ks + 1], sA);
                unsigned a11 = __shfl(pkB[2 * ks + 1], sA);
                unsigned b10 = __shfl(pkA[2 * ks + 1], sB);
                unsigned b11 = __shfl(pkB[2 * ks + 1], sB);
                w0 = hiT ? a10 : a00;
                w1 = hiT ? a11 : a01;
                w2 = hiT ? b10 : b00;
                w3 = hiT ? b11 : b01;
            } else {   // ks==6: T1=13 doesn't exist; lanes lg>=2 (kbase>=208) get 0
                w0 = hiT ? 0u : a00;
                w1 = hiT ? 0u : a01;
                w2 = hiT ? 0u : b00;
                w3 = hiT ? 0u : b01;
            }
            union { unsigned u[4]; bf16x8 v; } pu;
            pu.u[0] = w0; pu.u[1] = w1; pu.u[2] = w2; pu.u[3] = w3;
            bf16x8 pf = pu.v;
#pragma unroll
            for (int mt = 0; mt < 4; ++mt) {
                bf16x8 vf;
                if (kbase < 208)
                    vf = *reinterpret_cast<const bf16x8*>(&Vt[mt * 16 + lr][kbase]);
                else {
#pragma unroll
                    for (int j = 0; j < 8; ++j) vf[j] = (__bf16)0.f;
                }
                o[mt] = MFMA16(vf, pf, o[mt]);
            }
        }
        int qg = n0 + lr;
        if (qg < 198) {
            __bf16* dst = outp + ((size_t)b * 198 + qg) * 768 + h * 64;
#pragma unroll
            for (int mt = 0; mt < 4; ++mt) {
                bf16x4 pk;
#pragma unroll
                for (int r = 0; r < 4; ++r) pk[r] = (__bf16)o[mt][r];
                *reinterpret_cast<bf16x4*>(dst + mt * 16 + lg * 4) = pk;
            }
        }
    }
}

// ---------------------------------------------------------------------------
// CLS-row reweighting (masked_scatter flat-order semantics) — unchanged.
// ---------------------------------------------------------------------------
__global__ __launch_bounds__(64) void reweight_kernel(
    const float* __restrict__ p0, const float* __restrict__ mgb,
    const __bf16* __restrict__ vb, float* __restrict__ attn_out,
    __bf16* __restrict__ outp) {
    const int t = blockIdx.x;          // b*12 + h
    const int b = t / 12, h = t % 12;
    const int h2 = t >> 8, b2 = t & 255;
    const int lane = threadIdx.x;
    __shared__ float nr[198];
    const float* pr = p0 + (size_t)(b2 * 12 + h2) * 198;
    const float* mr = mgb + (size_t)b2 * 198;
    float w[4];
    float ssum = 0.f;
#pragma unroll
    for (int i = 0; i < 4; ++i) {
        int n = lane + 64 * i;
        float xv = (n < 198) ? pr[n] * mr[n] : 0.f;
        w[i] = xv;
        ssum += xv;
    }
#pragma unroll
    for (int m = 1; m < 64; m <<= 1) ssum += __shfl_xor(ssum, m);
    float inv = 1.f / ssum;
#pragma unroll
    for (int i = 0; i < 4; ++i) {
        int n = lane + 64 * i;
        if (n < 198) {
            float xv = w[i] * inv;
            nr[n] = xv;
            attn_out[(size_t)t * 198 + n] = xv;
        }
    }
    __syncthreads();
    const __bf16* vp = vb + (size_t)t * 198 * 64;
    float acc = 0.f;
    for (int n = 0; n < 198; ++n) acc += nr[n] * (float)vp[n * 64 + lane];
    outp[((size_t)b * 198) * 768 + h * 64 + lane] = (__bf16)acc;
}

// ---------------------------------------------------------------------------
// GEMM2 v8 (best measured): 128x128, 4 waves, 3 blocks/CU, BK=32 dbuf,
// counted vmcnt(4).
// ---------------------------------------------------------------------------
__global__ __launch_bounds__(256, 3) void gemm_proj_v8(
    const __bf16* __restrict__ A, const __bf16* __restrict__ wT,
    const float* __restrict__ bias, float* __restrict__ out) {
    __shared__ __bf16 As[2][128 * 32];
    __shared__ __bf16 Bs[2][128 * 32];
    const int bid = blockIdx.x;
    const int wg  = (bid & 7) * 297 + (bid >> 3);   // bijective: 2376 = 8*297
    const int brow = (wg / 6) * 128;
    const int bcol = (wg % 6) * 128;
    const int tid = threadIdx.x, lane = tid & 63, wid = tid >> 6;
    const int wm = wid >> 1, wn = wid & 1;
    const int lr = lane & 15, lg = lane >> 4;

    const int srow = tid >> 2;
    const int sslot = (tid & 3) ^ ((tid >> 3) & 3);
    const __bf16* aSrc = A  + (size_t)(brow + srow) * 768 + sslot * 8;
    const __bf16* bSrc = wT + (size_t)(bcol + srow) * 768 + sslot * 8;
    const int rkey = (lr >> 1) & 3;

    f32x4 acc[4][4] = {};

#define STAGE_P6(buf, kk0)                                                    \
    {                                                                         \
        __bf16* aD = &As[buf][wid * 512];                                     \
        __bf16* bD = &Bs[buf][wid * 512];                                     \
        GLOAD_LDS16(aSrc + (kk0), aD);                                        \
        GLOAD_LDS16(bSrc + (kk0), bD);                                        \
        GLOAD_LDS16(aSrc + (size_t)64 * 768 + (kk0), aD + 2048);              \
        GLOAD_LDS16(bSrc + (size_t)64 * 768 + (kk0), bD + 2048);              \
    }

#define COMPUTE_P6(buf)                                                       \
    {                                                                         \
        const __bf16* Ab = As[buf];                                           \
        const __bf16* Bb = Bs[buf];                                           \
        bf16x8 af[4], bfv[4];                                                 \
        _Pragma("unroll")                                                     \
        for (int nt = 0; nt < 4; ++nt)                                        \
            bfv[nt] = *reinterpret_cast<const bf16x8*>(                       \
                Bb + (wn * 64 + nt * 16 + lr) * 32 + ((lg ^ rkey) * 8));      \
        _Pragma("unroll")                                                     \
        for (int mt = 0; mt < 4; ++mt)                                        \
            af[mt] = *reinterpret_cast<const bf16x8*>(                        \
                Ab + (wm * 64 + mt * 16 + lr) * 32 + ((lg ^ rkey) * 8));      \
        __builtin_amdgcn_s_setprio(1);                                        \
        _Pragma("unroll")                                                     \
        for (int mt = 0; mt < 4; ++mt)                                        \
            _Pragma("unroll")                                                 \
            for (int nt = 0; nt < 4; ++nt)                                    \
                acc[mt][nt] = MFMA16(af[mt], bfv[nt], acc[mt][nt]);           \
        __builtin_amdgcn_s_setprio(0);                                        \
    }

    STAGE_P6(0, 0);
    STAGE_P6(1, 32);
    for (int tau = 0; tau < 24; ++tau) {
        if (tau == 23) asm volatile("s_waitcnt vmcnt(0)" ::: "memory");
        else           asm volatile("s_waitcnt vmcnt(4)" ::: "memory");
        __builtin_amdgcn_s_barrier();
        __builtin_amdgcn_sched_barrier(0);
        COMPUTE_P6(tau & 1);
        __builtin_amdgcn_sched_barrier(0);
        __builtin_amdgcn_s_barrier();
        __builtin_amdgcn_sched_barrier(0);
        if (tau < 22) STAGE_P6(tau & 1, (tau + 2) * 32);
    }
#undef STAGE_P6
#undef COMPUTE_P6

#pragma unroll
    for (int mt = 0; mt < 4; ++mt) {
#pragma unroll
        for (int nt = 0; nt < 4; ++nt) {
            int gcol = bcol + wn * 64 + nt * 16 + lr;
            float bv = bias[gcol];
#pragma unroll
            for (int r = 0; r < 4; ++r) {
                int grow = brow + wm * 64 + mt * 16 + lg * 4 + r;
                out[(size_t)grow * 768 + gcol] = acc[mt][nt][r] + bv;
            }
        }
    }
}

// ---------------------------------------------------------------------------
extern "C" void kernel_launch(void* const* d_in, const int* in_sizes, int n_in,
                              void* d_out, int out_size, void* d_ws, size_t ws_size,
                              hipStream_t stream) {
    const float* x      = (const float*)d_in[0];
    const float* w_qkv  = (const float*)d_in[1];
    const float* w_proj = (const float*)d_in[2];
    const float* b_proj = (const float*)d_in[3];
    const float* w_D    = (const float*)d_in[4];
    const float* b_D    = (const float*)d_in[5];
    const float* w_cen  = (const float*)d_in[6];
    const float* b_cen  = (const float*)d_in[7];

    float* out      = (float*)d_out;
    float* cen_out  = out;                    // [256,3,2]  = 1536
    float* attn_out = out + 1536;             // [256,12,198] = 608256
    float* proj_out = out + 1536 + 608256;    // [256,198,768]

    char* ws = (char*)d_ws;
    size_t off = 0;
    auto carve = [&](size_t bytes) {
        void* p = ws + off;
        off += (bytes + 255) & ~(size_t)255;
        return p;
    };
    __bf16* wqkvT  = (__bf16*)carve((size_t)2304 * 768 * 2);
    __bf16* wprojT = (__bf16*)carve((size_t)768 * 768 * 2);
    __bf16* qb     = (__bf16*)carve((size_t)3072 * 198 * 64 * 2);
    __bf16* kb     = (__bf16*)carve((size_t)3072 * 198 * 64 * 2);
    __bf16* vb     = (__bf16*)carve((size_t)3072 * 198 * 64 * 2);
    __bf16* outp   = (__bf16*)carve((size_t)50688 * 768 * 2);
    float*  q0     = (float*)carve((size_t)256 * 768 * 4);
    float*  mgb    = (float*)carve((size_t)256 * 198 * 4);
    float*  p0     = (float*)carve((size_t)3072 * 198 * 4);

    // xb aliases outp: xb is dead before attn_kernel writes outp (stream-ordered)
    __bf16* xb = outp;

    prep_kernel<<<2048 + 1728 + 576, 256, 0, stream>>>(x, xb, w_qkv, wqkvT, w_proj, wprojT);
    gemm_qkv_v7<<<1782, 512, 0, stream>>>(xb, wqkvT, qb, kb, vb, q0);
    mgb_kernel<<<256, 256, 0, stream>>>(q0, w_D, b_D, w_cen, b_cen, cen_out, mgb);
    attn_kernel<<<3072, 256, 0, stream>>>(qb, kb, vb, p0, outp);
    reweight_kernel<<<3072, 64, 0, stream>>>(p0, mgb, vb, attn_out, outp);
    gemm_proj_v8<<<2376, 256, 0, stream>>>(outp, wprojT, b_proj, proj_out);
}

// Round 17
// 498.072 us; speedup vs baseline: 1.1299x; 1.1299x over previous
//
#include <hip/hip_runtime.h>
#include <cstdint>
#include <cstddef>

typedef __attribute__((ext_vector_type(4))) float  f32x4;
typedef __attribute__((ext_vector_type(8))) __bf16 bf16x8;
typedef __attribute__((ext_vector_type(4))) __bf16 bf16x4;

#define MFMA16(A, B, C) __builtin_amdgcn_mfma_f32_16x16x32_bf16((A), (B), (C), 0, 0, 0)

// async global->LDS, 16B per lane, wave-uniform LDS base + lane*16
#define GLOAD_LDS16(gp, lp)                                        \
    __builtin_amdgcn_global_load_lds(                              \
        (const __attribute__((address_space(1))) void*)(gp),       \
        (__attribute__((address_space(3))) void*)(lp), 16, 0, 0)

// problem constants
#define NB 256
#define NN 198
#define NC 768
#define NH 12

// ---------------------------------------------------------------------------
// Merged prep: blocks [0,2048) grid-stride cast x f32->bf16 (16B/lane);
// blocks [2048,3776) transpose w_qkv; blocks [3776,4352) transpose w_proj.
// ---------------------------------------------------------------------------
__global__ __launch_bounds__(256) void prep_kernel(
    const float* __restrict__ x, __bf16* __restrict__ xb,
    const float* __restrict__ w_qkv, __bf16* __restrict__ wqkvT,
    const float* __restrict__ w_proj, __bf16* __restrict__ wprojT) {
    __shared__ __bf16 tile[32][33];
    const int blk = blockIdx.x;
    if (blk < 2048) {
        const int n8 = 50688 * 768 / 8;
        for (int i = blk * 256 + threadIdx.x; i < n8; i += 2048 * 256) {
            const float4 f0 = reinterpret_cast<const float4*>(x)[i * 2];
            const float4 f1 = reinterpret_cast<const float4*>(x)[i * 2 + 1];
            bf16x8 h;
            h[0] = (__bf16)f0.x; h[1] = (__bf16)f0.y; h[2] = (__bf16)f0.z; h[3] = (__bf16)f0.w;
            h[4] = (__bf16)f1.x; h[5] = (__bf16)f1.y; h[6] = (__bf16)f1.z; h[7] = (__bf16)f1.w;
            reinterpret_cast<bf16x8*>(xb)[i] = h;
        }
    } else {
        int tb = blk - 2048;
        const float* in;
        __bf16* outp_;
        int R, Cc;
        if (tb < 1728) { in = w_qkv; outp_ = wqkvT; R = 768; Cc = 2304; }
        else           { tb -= 1728; in = w_proj; outp_ = wprojT; R = 768; Cc = 768; }
        const int ntc = Cc >> 5;
        const int tc = tb % ntc, tr = tb / ntc;
        const int c0 = tc * 32, r0 = tr * 32;
        const int lx = threadIdx.x & 31, ly = threadIdx.x >> 5;   // 32 x 8
#pragma unroll
        for (int j = 0; j < 4; ++j)
            tile[ly + j * 8][lx] = (__bf16)in[(size_t)(r0 + ly + j * 8) * Cc + c0 + lx];
        __syncthreads();
#pragma unroll
        for (int j = 0; j < 4; ++j)
            outp_[(size_t)(c0 + ly + j * 8) * R + r0 + lx] = tile[lx][ly + j * 8];
    }
}

// ---------------------------------------------------------------------------
// GEMM v7 (best measured, reproduced r10/r12/r13/r15: ~260us, MfmaUtil ~30%):
// 256x256, 8 waves, BK=64 dbuf, counted vmcnt(8), 4-phase intra-iter
// pipeline with counted lgkmcnt.
// ---------------------------------------------------------------------------
__global__ __launch_bounds__(512, 2) void gemm_qkv_v7(
    const __bf16* __restrict__ xb, const __bf16* __restrict__ wT,
    __bf16* __restrict__ qb, __bf16* __restrict__ kb, __bf16* __restrict__ vb,
    float* __restrict__ q0) {
    __shared__ __bf16 As[2][256 * 64];
    __shared__ __bf16 Bs[2][256 * 64];
    const int bid = blockIdx.x;
    const int xcd = bid & 7, lin = bid >> 3;
    const int wgid = (xcd < 6 ? xcd * 223 : 6 * 223 + (xcd - 6) * 222) + lin;
    const int brow = (wgid / 9) * 256;
    const int bcol = (wgid % 9) * 256;
    const int tid = threadIdx.x, lane = tid & 63, wid = tid >> 6;
    const int wr = wid >> 2, wc = wid & 3;
    const int lr = lane & 15, lg = lane >> 4;

    const int srow = tid >> 3;
    const int sslot = (tid & 7) ^ ((tid >> 3) & 7);
    const __bf16* aSrc = xb + (size_t)(brow + srow) * 768 + sslot * 8;
    const __bf16* bSrc = wT + (size_t)(bcol + srow) * 768 + sslot * 8;
    const int key = lr & 7;

    f32x4 acc[8][4] = {};

#define STAGE7(buf, kk0)                                                       \
    {                                                                          \
        __bf16* aD = &As[buf][wid * 512];                                      \
        __bf16* bD = &Bs[buf][wid * 512];                                      \
        _Pragma("unroll")                                                      \
        for (int j = 0; j < 4; ++j) {                                          \
            GLOAD_LDS16(aSrc + (size_t)j * 64 * 768 + (kk0), aD + j * 4096);   \
            GLOAD_LDS16(bSrc + (size_t)j * 64 * 768 + (kk0), bD + j * 4096);   \
        }                                                                      \
    }

#define LDA7(f0, f1, f2, f3, m0)                                               \
    f0 = *reinterpret_cast<const bf16x8*>(                                     \
        Ab + (wr * 128 + (m0) * 16 + lr) * 64 + ((lg ^ key) * 8));             \
    f1 = *reinterpret_cast<const bf16x8*>(                                     \
        Ab + (wr * 128 + (m0) * 16 + lr) * 64 + (((4 + lg) ^ key) * 8));       \
    f2 = *reinterpret_cast<const bf16x8*>(                                     \
        Ab + (wr * 128 + (m0) * 16 + 16 + lr) * 64 + ((lg ^ key) * 8));        \
    f3 = *reinterpret_cast<const bf16x8*>(                                     \
        Ab + (wr * 128 + (m0) * 16 + 16 + lr) * 64 + (((4 + lg) ^ key) * 8));

#define MFMA_PHASE7(f0, f1, f2, f3, m0)                                        \
    __builtin_amdgcn_s_setprio(1);                                             \
    _Pragma("unroll")                                                          \
    for (int nt = 0; nt < 4; ++nt) acc[(m0)][nt]     = MFMA16(f0, bfr[0][nt], acc[(m0)][nt]);     \
    _Pragma("unroll")                                                          \
    for (int nt = 0; nt < 4; ++nt) acc[(m0)][nt]     = MFMA16(f1, bfr[1][nt], acc[(m0)][nt]);     \
    _Pragma("unroll")                                                          \
    for (int nt = 0; nt < 4; ++nt) acc[(m0) + 1][nt] = MFMA16(f2, bfr[0][nt], acc[(m0) + 1][nt]); \
    _Pragma("unroll")                                                          \
    for (int nt = 0; nt < 4; ++nt) acc[(m0) + 1][nt] = MFMA16(f3, bfr[1][nt], acc[(m0) + 1][nt]); \
    __builtin_amdgcn_s_setprio(0);

    STAGE7(0, 0);
    STAGE7(1, 64);
    for (int tau = 0; tau < 12; ++tau) {
        const int b = tau & 1;
        if (tau == 11) asm volatile("s_waitcnt vmcnt(0)" ::: "memory");
        else           asm volatile("s_waitcnt vmcnt(8)" ::: "memory");
        __builtin_amdgcn_s_barrier();
        __builtin_amdgcn_sched_barrier(0);
        const __bf16* Ab = As[b];
        const __bf16* Bb = Bs[b];
        bf16x8 bfr[2][4];
#pragma unroll
        for (int kk = 0; kk < 2; ++kk)
#pragma unroll
            for (int nt = 0; nt < 4; ++nt)
                bfr[kk][nt] = *reinterpret_cast<const bf16x8*>(
                    Bb + (wc * 64 + nt * 16 + lr) * 64 + (((kk * 4 + lg) ^ key) * 8));
        bf16x8 a0, a1, a2, a3, b0, b1, b2, b3;
        LDA7(a0, a1, a2, a3, 0);
        LDA7(b0, b1, b2, b3, 2);
        asm volatile("s_waitcnt lgkmcnt(4)" ::: "memory");
        __builtin_amdgcn_sched_barrier(0);
        MFMA_PHASE7(a0, a1, a2, a3, 0);
        LDA7(a0, a1, a2, a3, 4);
        asm volatile("s_waitcnt lgkmcnt(4)" ::: "memory");
        __builtin_amdgcn_sched_barrier(0);
        MFMA_PHASE7(b0, b1, b2, b3, 2);
        LDA7(b0, b1, b2, b3, 6);
        asm volatile("s_waitcnt lgkmcnt(4)" ::: "memory");
        __builtin_amdgcn_sched_barrier(0);
        MFMA_PHASE7(a0, a1, a2, a3, 4);
        asm volatile("s_waitcnt lgkmcnt(0)" ::: "memory");
        __builtin_amdgcn_sched_barrier(0);
        __builtin_amdgcn_s_barrier();
        __builtin_amdgcn_sched_barrier(0);
        if (tau < 10) STAGE7(b, (tau + 2) * 64);
        MFMA_PHASE7(b0, b1, b2, b3, 6);
    }
#undef STAGE7

    // epilogue: D layout row=(lane>>4)*4+reg, col=lane&15  [m89-verified]
#pragma unroll
    for (int mt = 0; mt < 8; ++mt) {
        int grow0 = brow + wr * 128 + mt * 16 + lg * 4;
        int bbs[4], nns[4];
#pragma unroll
        for (int r = 0; r < 4; ++r) {
            bbs[r] = (grow0 + r) / 198;
            nns[r] = (grow0 + r) % 198;
        }
#pragma unroll
        for (int nt = 0; nt < 4; ++nt) {
            int gcol = bcol + wc * 64 + nt * 16 + lr;   // 0..2303
            int sidx = gcol / 768;
            int rem  = gcol % 768;                      // h*64+d
            __bf16* dstbuf = (sidx == 0) ? qb : (sidx == 1) ? kb : vb;
            int hh = rem >> 6, dd = rem & 63;
#pragma unroll
            for (int r = 0; r < 4; ++r) {
                float val = acc[mt][nt][r];
                dstbuf[(((size_t)bbs[r] * 12 + hh) * 198 + nns[r]) * 64 + dd] = (__bf16)val;
                if (sidx == 0 && nns[r] == 0) q0[bbs[r] * 768 + rem] = val;
            }
        }
    }
}

// ---------------------------------------------------------------------------
// Per-batch head: D/cen sigmoid heads from q0, then mixture-of-gaussian mgb.
// ---------------------------------------------------------------------------
__global__ __launch_bounds__(256) void mgb_kernel(
    const float* __restrict__ q0, const float* __restrict__ wD,
    const float* __restrict__ bD, const float* __restrict__ wcen,
    const float* __restrict__ bcen, float* __restrict__ cen_out,
    float* __restrict__ mgb) {
    const int b = blockIdx.x, t = threadIdx.x;
    __shared__ float qs[768];
    __shared__ float red[256];
    __shared__ float vals[9];
    qs[t]       = q0[b * 768 + t];
    qs[t + 256] = q0[b * 768 + t + 256];
    qs[t + 512] = q0[b * 768 + t + 512];
    __syncthreads();
    for (int j = 0; j < 9; ++j) {
        float p;
        if (j < 3)
            p = qs[t] * wD[t * 3 + j] + qs[t + 256] * wD[(t + 256) * 3 + j] +
                qs[t + 512] * wD[(t + 512) * 3 + j];
        else {
            int c = j - 3;
            p = qs[t] * wcen[t * 6 + c] + qs[t + 256] * wcen[(t + 256) * 6 + c] +
                qs[t + 512] * wcen[(t + 512) * 6 + c];
        }
        red[t] = p;
        __syncthreads();
        for (int off = 128; off > 0; off >>= 1) {
            if (t < off) red[t] += red[t + off];
            __syncthreads();
        }
        if (t == 0) {
            float bias = (j < 3) ? bD[j] : bcen[j - 3];
            vals[j] = 1.f / (1.f + __expf(-(red[0] + bias)));
        }
        __syncthreads();
    }
    if (t < 6) cen_out[b * 6 + t] = vals[3 + t];

    float e3[3] = {0.f, 0.f, 0.f};
    if (t < 196) {
        float gx = 8.f + 16.f * (float)(t / 14);   // GRIDS x-major
        float gy = 8.f + 16.f * (float)(t % 14);
#pragma unroll
        for (int j = 0; j < 3; ++j) {
            float sig = 112.f * vals[j];
            float cx = vals[3 + 2 * j] * 223.f;
            float cy = vals[3 + 2 * j + 1] * 223.f;
            float dx = cx - gx, dy = cy - gy;
            e3[j] = __expf(-(dx * dx + dy * dy) / (2.f * sig * sig));
        }
    }
    float js[3];
    for (int j = 0; j < 3; ++j) {
        red[t] = e3[j];
        __syncthreads();
        for (int off = 128; off > 0; off >>= 1) {
            if (t < off) red[t] += red[t + off];
            __syncthreads();
        }
        js[j] = red[0];
        __syncthreads();
    }
    if (t < 196) {
        float m = (e3[0] / js[0] + e3[1] / js[1] + e3[2] / js[2]) * (1.f / 3.f);
        mgb[(size_t)b * 198 + 2 + t] = m;
    }
    if (t < 2) mgb[(size_t)b * 198 + t] = 1.f;
}

// ---------------------------------------------------------------------------
// Attention per (b,h) v9 (best measured; r16's shuffle-PV REVERTED — VALU-
// bound, +60us): K staged in LDS via async global_load_lds with verified
// XOR-swizzle; V transposed in LDS; swapped-QK^T in-register softmax;
// P through per-wave LDS for the PV A-operand.
// ---------------------------------------------------------------------------
__global__ __launch_bounds__(256) void attn_kernel(
    const __bf16* __restrict__ qb, const __bf16* __restrict__ kb,
    const __bf16* __restrict__ vb, float* __restrict__ p0,
    __bf16* __restrict__ outp) {
    __shared__ __bf16 Klds[208 * 64];     // rows 198..207 duplicate row 197
    __shared__ __bf16 Vt[64][216];
    __shared__ __bf16 Plds[4][16][216];
    const int bh = blockIdx.x;
    const int b = bh / 12, h = bh % 12;
    const __bf16* Qp = qb + (size_t)bh * NN * 64;
    const __bf16* Kp = kb + (size_t)bh * NN * 64;
    const __bf16* Vp = vb + (size_t)bh * NN * 64;
    const int tid = threadIdx.x, lane = tid & 63, wid = tid >> 6;
    const int lr = lane & 15, lg = lane >> 4;

    {
        const int rsub = wid * 8 + (lane >> 3);            // 0..31 within issue
        const int sl   = ((lane & 7) ^ ((lane >> 3) & 7)) * 8;
#pragma unroll
        for (int i = 0; i < 7; ++i) {
            if (i < 6 || wid < 2) {
                int row = i * 32 + rsub;
                int rowc = row < 198 ? row : 197;
                GLOAD_LDS16(Kp + (size_t)rowc * 64 + sl,
                            Klds + (size_t)i * 2048 + wid * 512);
            }
        }
    }

    for (int i = tid; i < 104 * 8; i += 256) {
        int key2 = (i >> 3) * 2, d0 = (i & 7) << 3;
        int kr0 = key2 < 198 ? key2 : 197;
        int kr1 = key2 + 1 < 198 ? key2 + 1 : 197;
        bf16x8 h0 = *reinterpret_cast<const bf16x8*>(Vp + kr0 * 64 + d0);
        bf16x8 h1 = *reinterpret_cast<const bf16x8*>(Vp + kr1 * 64 + d0);
#pragma unroll
        for (int j = 0; j < 8; ++j) {
            union { __bf16 hh[2]; unsigned u; } pk;
            pk.hh[0] = h0[j]; pk.hh[1] = h1[j];
            *reinterpret_cast<unsigned*>(&Vt[d0 + j][key2]) = pk.u;
        }
    }
    __syncthreads();   // drains vmcnt (K stage) + lgkm (V writes)

    for (int ch = wid; ch < 13; ch += 4) {
        int n0 = ch * 16;
        int qrow = n0 + lr; if (qrow > 197) qrow = 197;
        bf16x8 qf0 = *reinterpret_cast<const bf16x8*>(Qp + qrow * 64 + lg * 8);
        bf16x8 qf1 = *reinterpret_cast<const bf16x8*>(Qp + qrow * 64 + 32 + lg * 8);
        f32x4 sa[13];
#pragma unroll
        for (int t2 = 0; t2 < 13; ++t2) {
            int krow = t2 * 16 + lr;                       // <= 207, in Klds
            const int kx = lr & 7;                         // krow & 7
            bf16x8 kf0 = *reinterpret_cast<const bf16x8*>(
                Klds + krow * 64 + ((lg ^ kx) * 8));
            bf16x8 kf1 = *reinterpret_cast<const bf16x8*>(
                Klds + krow * 64 + (((4 + lg) ^ kx) * 8));
            f32x4 a = (f32x4){0.f, 0.f, 0.f, 0.f};
            a = MFMA16(kf0, qf0, a);
            a = MFMA16(kf1, qf1, a);
            sa[t2] = a;
        }
        float rmax = -1e30f;
#pragma unroll
        for (int t2 = 0; t2 < 13; ++t2)
#pragma unroll
            for (int r = 0; r < 4; ++r) {
                int key = t2 * 16 + lg * 4 + r;
                float vv = (key < 198) ? sa[t2][r] * 0.125f : -1e30f;
                sa[t2][r] = vv;
                rmax = fmaxf(rmax, vv);
            }
        rmax = fmaxf(rmax, __shfl_xor(rmax, 16));
        rmax = fmaxf(rmax, __shfl_xor(rmax, 32));
        float rsum = 0.f;
#pragma unroll
        for (int t2 = 0; t2 < 13; ++t2)
#pragma unroll
            for (int r = 0; r < 4; ++r) {
                float e = __expf(sa[t2][r] - rmax);
                sa[t2][r] = e;
                rsum += e;
            }
        rsum += __shfl_xor(rsum, 16);
        rsum += __shfl_xor(rsum, 32);
        float inv = 1.f / rsum;

        if (ch == 0 && lr == 0) {
#pragma unroll
            for (int t2 = 0; t2 < 13; ++t2)
#pragma unroll
                for (int r = 0; r < 4; ++r) {
                    int key = t2 * 16 + lg * 4 + r;
                    if (key < 198) p0[(size_t)bh * 198 + key] = sa[t2][r] * inv;
                }
        }
#pragma unroll
        for (int t2 = 0; t2 < 13; ++t2) {
            bf16x4 pk;
#pragma unroll
            for (int r = 0; r < 4; ++r) pk[r] = (__bf16)(sa[t2][r] * inv);
            *reinterpret_cast<bf16x4*>(&Plds[wid][lr][t2 * 16 + lg * 4]) = pk;
        }
        asm volatile("s_waitcnt lgkmcnt(0)" ::: "memory");

        f32x4 o[4];
#pragma unroll
        for (int mt = 0; mt < 4; ++mt) o[mt] = (f32x4){0.f, 0.f, 0.f, 0.f};
#pragma unroll
        for (int ks = 0; ks < 7; ++ks) {
            int kbase = ks * 32 + lg * 8;
            bf16x8 pf;
            if (kbase < 208)
                pf = *reinterpret_cast<const bf16x8*>(&Plds[wid][lr][kbase]);
            else {
#pragma unroll
                for (int j = 0; j < 8; ++j) pf[j] = (__bf16)0.f;
            }
#pragma unroll
            for (int mt = 0; mt < 4; ++mt) {
                bf16x8 vf;
                if (kbase < 208)
                    vf = *reinterpret_cast<const bf16x8*>(&Vt[mt * 16 + lr][kbase]);
                else {
#pragma unroll
                    for (int j = 0; j < 8; ++j) vf[j] = (__bf16)0.f;
                }
                o[mt] = MFMA16(vf, pf, o[mt]);
            }
        }
        int qg = n0 + lr;
        if (qg < 198) {
            __bf16* dst = outp + ((size_t)b * 198 + qg) * 768 + h * 64;
#pragma unroll
            for (int mt = 0; mt < 4; ++mt) {
                bf16x4 pk;
#pragma unroll
                for (int r = 0; r < 4; ++r) pk[r] = (__bf16)o[mt][r];
                *reinterpret_cast<bf16x4*>(dst + mt * 16 + lg * 4) = pk;
            }
        }
    }
}

// ---------------------------------------------------------------------------
// CLS-row reweighting (masked_scatter flat-order semantics) — unchanged.
// ---------------------------------------------------------------------------
__global__ __launch_bounds__(64) void reweight_kernel(
    const float* __restrict__ p0, const float* __restrict__ mgb,
    const __bf16* __restrict__ vb, float* __restrict__ attn_out,
    __bf16* __restrict__ outp) {
    const int t = blockIdx.x;          // b*12 + h
    const int b = t / 12, h = t % 12;
    const int h2 = t >> 8, b2 = t & 255;
    const int lane = threadIdx.x;
    __shared__ float nr[198];
    const float* pr = p0 + (size_t)(b2 * 12 + h2) * 198;
    const float* mr = mgb + (size_t)b2 * 198;
    float w[4];
    float ssum = 0.f;
#pragma unroll
    for (int i = 0; i < 4; ++i) {
        int n = lane + 64 * i;
        float xv = (n < 198) ? pr[n] * mr[n] : 0.f;
        w[i] = xv;
        ssum += xv;
    }
#pragma unroll
    for (int m = 1; m < 64; m <<= 1) ssum += __shfl_xor(ssum, m);
    float inv = 1.f / ssum;
#pragma unroll
    for (int i = 0; i < 4; ++i) {
        int n = lane + 64 * i;
        if (n < 198) {
            float xv = w[i] * inv;
            nr[n] = xv;
            attn_out[(size_t)t * 198 + n] = xv;
        }
    }
    __syncthreads();
    const __bf16* vp = vb + (size_t)t * 198 * 64;
    float acc = 0.f;
    for (int n = 0; n < 198; ++n) acc += nr[n] * (float)vp[n * 64 + lane];
    outp[((size_t)b * 198) * 768 + h * 64 + lane] = (__bf16)acc;
}

// ---------------------------------------------------------------------------
// GEMM2 v8 (best measured): 128x128, 4 waves, 3 blocks/CU, BK=32 dbuf,
// counted vmcnt(4).
// ---------------------------------------------------------------------------
__global__ __launch_bounds__(256, 3) void gemm_proj_v8(
    const __bf16* __restrict__ A, const __bf16* __restrict__ wT,
    const float* __restrict__ bias, float* __restrict__ out) {
    __shared__ __bf16 As[2][128 * 32];
    __shared__ __bf16 Bs[2][128 * 32];
    const int bid = blockIdx.x;
    const int wg  = (bid & 7) * 297 + (bid >> 3);   // bijective: 2376 = 8*297
    const int brow = (wg / 6) * 128;
    const int bcol = (wg % 6) * 128;
    const int tid = threadIdx.x, lane = tid & 63, wid = tid >> 6;
    const int wm = wid >> 1, wn = wid & 1;
    const int lr = lane & 15, lg = lane >> 4;

    const int srow = tid >> 2;
    const int sslot = (tid & 3) ^ ((tid >> 3) & 3);
    const __bf16* aSrc = A  + (size_t)(brow + srow) * 768 + sslot * 8;
    const __bf16* bSrc = wT + (size_t)(bcol + srow) * 768 + sslot * 8;
    const int rkey = (lr >> 1) & 3;

    f32x4 acc[4][4] = {};

#define STAGE_P6(buf, kk0)                                                    \
    {                                                                         \
        __bf16* aD = &As[buf][wid * 512];                                     \
        __bf16* bD = &Bs[buf][wid * 512];                                     \
        GLOAD_LDS16(aSrc + (kk0), aD);                                        \
        GLOAD_LDS16(bSrc + (kk0), bD);                                        \
        GLOAD_LDS16(aSrc + (size_t)64 * 768 + (kk0), aD + 2048);              \
        GLOAD_LDS16(bSrc + (size_t)64 * 768 + (kk0), bD + 2048);              \
    }

#define COMPUTE_P6(buf)                                                       \
    {                                                                         \
        const __bf16* Ab = As[buf];                                           \
        const __bf16* Bb = Bs[buf];                                           \
        bf16x8 af[4], bfv[4];                                                 \
        _Pragma("unroll")                                                     \
        for (int nt = 0; nt < 4; ++nt)                                        \
            bfv[nt] = *reinterpret_cast<const bf16x8*>(                       \
                Bb + (wn * 64 + nt * 16 + lr) * 32 + ((lg ^ rkey) * 8));      \
        _Pragma("unroll")                                                     \
        for (int mt = 0; mt < 4; ++mt)                                        \
            af[mt] = *reinterpret_cast<const bf16x8*>(                        \
                Ab + (wm * 64 + mt * 16 + lr) * 32 + ((lg ^ rkey) * 8));      \
        __builtin_amdgcn_s_setprio(1);                                        \
        _Pragma("unroll")                                                     \
        for (int mt = 0; mt < 4; ++mt)                                        \
            _Pragma("unroll")                                                 \
            for (int nt = 0; nt < 4; ++nt)                                    \
                acc[mt][nt] = MFMA16(af[mt], bfv[nt], acc[mt][nt]);           \
        __builtin_amdgcn_s_setprio(0);                                        \
    }

    STAGE_P6(0, 0);
    STAGE_P6(1, 32);
    for (int tau = 0; tau < 24; ++tau) {
        if (tau == 23) asm volatile("s_waitcnt vmcnt(0)" ::: "memory");
        else           asm volatile("s_waitcnt vmcnt(4)" ::: "memory");
        __builtin_amdgcn_s_barrier();
        __builtin_amdgcn_sched_barrier(0);
        COMPUTE_P6(tau & 1);
        __builtin_amdgcn_sched_barrier(0);
        __builtin_amdgcn_s_barrier();
        __builtin_amdgcn_sched_barrier(0);
        if (tau < 22) STAGE_P6(tau & 1, (tau + 2) * 32);
    }
#undef STAGE_P6
#undef COMPUTE_P6

#pragma unroll
    for (int mt = 0; mt < 4; ++mt) {
#pragma unroll
        for (int nt = 0; nt < 4; ++nt) {
            int gcol = bcol + wn * 64 + nt * 16 + lr;
            float bv = bias[gcol];
#pragma unroll
            for (int r = 0; r < 4; ++r) {
                int grow = brow + wm * 64 + mt * 16 + lg * 4 + r;
                out[(size_t)grow * 768 + gcol] = acc[mt][nt][r] + bv;
            }
        }
    }
}

// ---------------------------------------------------------------------------
extern "C" void kernel_launch(void* const* d_in, const int* in_sizes, int n_in,
                              void* d_out, int out_size, void* d_ws, size_t ws_size,
                              hipStream_t stream) {
    const float* x      = (const float*)d_in[0];
    const float* w_qkv  = (const float*)d_in[1];
    const float* w_proj = (const float*)d_in[2];
    const float* b_proj = (const float*)d_in[3];
    const float* w_D    = (const float*)d_in[4];
    const float* b_D    = (const float*)d_in[5];
    const float* w_cen  = (const float*)d_in[6];
    const float* b_cen  = (const float*)d_in[7];

    float* out      = (float*)d_out;
    float* cen_out  = out;                    // [256,3,2]  = 1536
    float* attn_out = out + 1536;             // [256,12,198] = 608256
    float* proj_out = out + 1536 + 608256;    // [256,198,768]

    char* ws = (char*)d_ws;
    size_t off = 0;
    auto carve = [&](size_t bytes) {
        void* p = ws + off;
        off += (bytes + 255) & ~(size_t)255;
        return p;
    };
    __bf16* wqkvT  = (__bf16*)carve((size_t)2304 * 768 * 2);
    __bf16* wprojT = (__bf16*)carve((size_t)768 * 768 * 2);
    __bf16* qb     = (__bf16*)carve((size_t)3072 * 198 * 64 * 2);
    __bf16* kb     = (__bf16*)carve((size_t)3072 * 198 * 64 * 2);
    __bf16* vb     = (__bf16*)carve((size_t)3072 * 198 * 64 * 2);
    __bf16* outp   = (__bf16*)carve((size_t)50688 * 768 * 2);
    float*  q0     = (float*)carve((size_t)256 * 768 * 4);
    float*  mgb    = (float*)carve((size_t)256 * 198 * 4);
    float*  p0     = (float*)carve((size_t)3072 * 198 * 4);

    // xb aliases outp: xb is dead before attn_kernel writes outp (stream-ordered)
    __bf16* xb = outp;

    prep_kernel<<<2048 + 1728 + 576, 256, 0, stream>>>(x, xb, w_qkv, wqkvT, w_proj, wprojT);
    gemm_qkv_v7<<<1782, 512, 0, stream>>>(xb, wqkvT, qb, kb, vb, q0);
    mgb_kernel<<<256, 256, 0, stream>>>(q0, w_D, b_D, w_cen, b_cen, cen_out, mgb);
    attn_kernel<<<3072, 256, 0, stream>>>(qb, kb, vb, p0, outp);
    reweight_kernel<<<3072, 64, 0, stream>>>(p0, mgb, vb, attn_out, outp);
    gemm_proj_v8<<<2376, 256, 0, stream>>>(outp, wprojT, b_proj, proj_out);
}

// Round 18
// 493.712 us; speedup vs baseline: 1.1399x; 1.0088x over previous
//
#include <hip/hip_runtime.h>
#include <cstdint>
#include <cstddef>

typedef __attribute__((ext_vector_type(4))) float  f32x4;
typedef __attribute__((ext_vector_type(8))) __bf16 bf16x8;
typedef __attribute__((ext_vector_type(4))) __bf16 bf16x4;

#define MFMA16(A, B, C) __builtin_amdgcn_mfma_f32_16x16x32_bf16((A), (B), (C), 0, 0, 0)

// async global->LDS, 16B per lane, wave-uniform LDS base + lane*16
#define GLOAD_LDS16(gp, lp)                                        \
    __builtin_amdgcn_global_load_lds(                              \
        (const __attribute__((address_space(1))) void*)(gp),       \
        (__attribute__((address_space(3))) void*)(lp), 16, 0, 0)

// problem constants
#define NB 256
#define NN 198
#define NC 768
#define NH 12

// ---------------------------------------------------------------------------
// Merged prep: blocks [0,2048) grid-stride cast x f32->bf16 (16B/lane);
// blocks [2048,3776) transpose w_qkv; blocks [3776,4352) transpose w_proj.
// ---------------------------------------------------------------------------
__global__ __launch_bounds__(256) void prep_kernel(
    const float* __restrict__ x, __bf16* __restrict__ xb,
    const float* __restrict__ w_qkv, __bf16* __restrict__ wqkvT,
    const float* __restrict__ w_proj, __bf16* __restrict__ wprojT) {
    __shared__ __bf16 tile[32][33];
    const int blk = blockIdx.x;
    if (blk < 2048) {
        const int n8 = 50688 * 768 / 8;
        for (int i = blk * 256 + threadIdx.x; i < n8; i += 2048 * 256) {
            const float4 f0 = reinterpret_cast<const float4*>(x)[i * 2];
            const float4 f1 = reinterpret_cast<const float4*>(x)[i * 2 + 1];
            bf16x8 h;
            h[0] = (__bf16)f0.x; h[1] = (__bf16)f0.y; h[2] = (__bf16)f0.z; h[3] = (__bf16)f0.w;
            h[4] = (__bf16)f1.x; h[5] = (__bf16)f1.y; h[6] = (__bf16)f1.z; h[7] = (__bf16)f1.w;
            reinterpret_cast<bf16x8*>(xb)[i] = h;
        }
    } else {
        int tb = blk - 2048;
        const float* in;
        __bf16* outp_;
        int R, Cc;
        if (tb < 1728) { in = w_qkv; outp_ = wqkvT; R = 768; Cc = 2304; }
        else           { tb -= 1728; in = w_proj; outp_ = wprojT; R = 768; Cc = 768; }
        const int ntc = Cc >> 5;
        const int tc = tb % ntc, tr = tb / ntc;
        const int c0 = tc * 32, r0 = tr * 32;
        const int lx = threadIdx.x & 31, ly = threadIdx.x >> 5;   // 32 x 8
#pragma unroll
        for (int j = 0; j < 4; ++j)
            tile[ly + j * 8][lx] = (__bf16)in[(size_t)(r0 + ly + j * 8) * Cc + c0 + lx];
        __syncthreads();
#pragma unroll
        for (int j = 0; j < 4; ++j)
            outp_[(size_t)(c0 + ly + j * 8) * R + r0 + lx] = tile[lx][ly + j * 8];
    }
}

// ---------------------------------------------------------------------------
// GEMM v7 (best measured, reproduced r10/r12/r13/r15/r17: ~260us, MfmaUtil
// ~30%): 256x256, 8 waves, BK=64 dbuf, counted vmcnt(8), 4-phase intra-iter
// pipeline with counted lgkmcnt.
// ---------------------------------------------------------------------------
__global__ __launch_bounds__(512, 2) void gemm_qkv_v7(
    const __bf16* __restrict__ xb, const __bf16* __restrict__ wT,
    __bf16* __restrict__ qb, __bf16* __restrict__ kb, __bf16* __restrict__ vb,
    float* __restrict__ q0) {
    __shared__ __bf16 As[2][256 * 64];
    __shared__ __bf16 Bs[2][256 * 64];
    const int bid = blockIdx.x;
    const int xcd = bid & 7, lin = bid >> 3;
    const int wgid = (xcd < 6 ? xcd * 223 : 6 * 223 + (xcd - 6) * 222) + lin;
    const int brow = (wgid / 9) * 256;
    const int bcol = (wgid % 9) * 256;
    const int tid = threadIdx.x, lane = tid & 63, wid = tid >> 6;
    const int wr = wid >> 2, wc = wid & 3;
    const int lr = lane & 15, lg = lane >> 4;

    const int srow = tid >> 3;
    const int sslot = (tid & 7) ^ ((tid >> 3) & 7);
    const __bf16* aSrc = xb + (size_t)(brow + srow) * 768 + sslot * 8;
    const __bf16* bSrc = wT + (size_t)(bcol + srow) * 768 + sslot * 8;
    const int key = lr & 7;

    f32x4 acc[8][4] = {};

#define STAGE7(buf, kk0)                                                       \
    {                                                                          \
        __bf16* aD = &As[buf][wid * 512];                                      \
        __bf16* bD = &Bs[buf][wid * 512];                                      \
        _Pragma("unroll")                                                      \
        for (int j = 0; j < 4; ++j) {                                          \
            GLOAD_LDS16(aSrc + (size_t)j * 64 * 768 + (kk0), aD + j * 4096);   \
            GLOAD_LDS16(bSrc + (size_t)j * 64 * 768 + (kk0), bD + j * 4096);   \
        }                                                                      \
    }

#define LDA7(f0, f1, f2, f3, m0)                                               \
    f0 = *reinterpret_cast<const bf16x8*>(                                     \
        Ab + (wr * 128 + (m0) * 16 + lr) * 64 + ((lg ^ key) * 8));             \
    f1 = *reinterpret_cast<const bf16x8*>(                                     \
        Ab + (wr * 128 + (m0) * 16 + lr) * 64 + (((4 + lg) ^ key) * 8));       \
    f2 = *reinterpret_cast<const bf16x8*>(                                     \
        Ab + (wr * 128 + (m0) * 16 + 16 + lr) * 64 + ((lg ^ key) * 8));        \
    f3 = *reinterpret_cast<const bf16x8*>(                                     \
        Ab + (wr * 128 + (m0) * 16 + 16 + lr) * 64 + (((4 + lg) ^ key) * 8));

#define MFMA_PHASE7(f0, f1, f2, f3, m0)                                        \
    __builtin_amdgcn_s_setprio(1);                                             \
    _Pragma("unroll")                                                          \
    for (int nt = 0; nt < 4; ++nt) acc[(m0)][nt]     = MFMA16(f0, bfr[0][nt], acc[(m0)][nt]);     \
    _Pragma("unroll")                                                          \
    for (int nt = 0; nt < 4; ++nt) acc[(m0)][nt]     = MFMA16(f1, bfr[1][nt], acc[(m0)][nt]);     \
    _Pragma("unroll")                                                          \
    for (int nt = 0; nt < 4; ++nt) acc[(m0) + 1][nt] = MFMA16(f2, bfr[0][nt], acc[(m0) + 1][nt]); \
    _Pragma("unroll")                                                          \
    for (int nt = 0; nt < 4; ++nt) acc[(m0) + 1][nt] = MFMA16(f3, bfr[1][nt], acc[(m0) + 1][nt]); \
    __builtin_amdgcn_s_setprio(0);

    STAGE7(0, 0);
    STAGE7(1, 64);
    for (int tau = 0; tau < 12; ++tau) {
        const int b = tau & 1;
        if (tau == 11) asm volatile("s_waitcnt vmcnt(0)" ::: "memory");
        else           asm volatile("s_waitcnt vmcnt(8)" ::: "memory");
        __builtin_amdgcn_s_barrier();
        __builtin_amdgcn_sched_barrier(0);
        const __bf16* Ab = As[b];
        const __bf16* Bb = Bs[b];
        bf16x8 bfr[2][4];
#pragma unroll
        for (int kk = 0; kk < 2; ++kk)
#pragma unroll
            for (int nt = 0; nt < 4; ++nt)
                bfr[kk][nt] = *reinterpret_cast<const bf16x8*>(
                    Bb + (wc * 64 + nt * 16 + lr) * 64 + (((kk * 4 + lg) ^ key) * 8));
        bf16x8 a0, a1, a2, a3, b0, b1, b2, b3;
        LDA7(a0, a1, a2, a3, 0);
        LDA7(b0, b1, b2, b3, 2);
        asm volatile("s_waitcnt lgkmcnt(4)" ::: "memory");
        __builtin_amdgcn_sched_barrier(0);
        MFMA_PHASE7(a0, a1, a2, a3, 0);
        LDA7(a0, a1, a2, a3, 4);
        asm volatile("s_waitcnt lgkmcnt(4)" ::: "memory");
        __builtin_amdgcn_sched_barrier(0);
        MFMA_PHASE7(b0, b1, b2, b3, 2);
        LDA7(b0, b1, b2, b3, 6);
        asm volatile("s_waitcnt lgkmcnt(4)" ::: "memory");
        __builtin_amdgcn_sched_barrier(0);
        MFMA_PHASE7(a0, a1, a2, a3, 4);
        asm volatile("s_waitcnt lgkmcnt(0)" ::: "memory");
        __builtin_amdgcn_sched_barrier(0);
        __builtin_amdgcn_s_barrier();
        __builtin_amdgcn_sched_barrier(0);
        if (tau < 10) STAGE7(b, (tau + 2) * 64);
        MFMA_PHASE7(b0, b1, b2, b3, 6);
    }
#undef STAGE7

    // epilogue: D layout row=(lane>>4)*4+reg, col=lane&15  [m89-verified]
#pragma unroll
    for (int mt = 0; mt < 8; ++mt) {
        int grow0 = brow + wr * 128 + mt * 16 + lg * 4;
        int bbs[4], nns[4];
#pragma unroll
        for (int r = 0; r < 4; ++r) {
            bbs[r] = (grow0 + r) / 198;
            nns[r] = (grow0 + r) % 198;
        }
#pragma unroll
        for (int nt = 0; nt < 4; ++nt) {
            int gcol = bcol + wc * 64 + nt * 16 + lr;   // 0..2303
            int sidx = gcol / 768;
            int rem  = gcol % 768;                      // h*64+d
            __bf16* dstbuf = (sidx == 0) ? qb : (sidx == 1) ? kb : vb;
            int hh = rem >> 6, dd = rem & 63;
#pragma unroll
            for (int r = 0; r < 4; ++r) {
                float val = acc[mt][nt][r];
                dstbuf[(((size_t)bbs[r] * 12 + hh) * 198 + nns[r]) * 64 + dd] = (__bf16)val;
                if (sidx == 0 && nns[r] == 0) q0[bbs[r] * 768 + rem] = val;
            }
        }
    }
}

// ---------------------------------------------------------------------------
// Attention per (b,h) v9 + fused mgb: blocks [0,3072) run the best-measured
// attn path (K-LDS swizzled, V^T in LDS, swapped-QK^T softmax, P via LDS);
// blocks [3072,3328) run the per-batch mgb head, with its small scratch
// OVERLAID on Klds (adds 0 LDS bytes — attn is exactly 2 blocks/CU at 80KB).
// Saves one graph-node launch gap; both paths byte-identical to r13/r15/r17.
// ---------------------------------------------------------------------------
__global__ __launch_bounds__(256) void attn_mgb_kernel(
    const __bf16* __restrict__ qb, const __bf16* __restrict__ kb,
    const __bf16* __restrict__ vb, float* __restrict__ p0,
    __bf16* __restrict__ outp,
    const float* __restrict__ q0, const float* __restrict__ wD,
    const float* __restrict__ bD, const float* __restrict__ wcen,
    const float* __restrict__ bcen, float* __restrict__ cen_out,
    float* __restrict__ mgb) {
    __shared__ __bf16 Klds[208 * 64];     // rows 198..207 duplicate row 197
    __shared__ __bf16 Vt[64][216];
    __shared__ __bf16 Plds[4][16][216];

    if (blockIdx.x >= 3072) {
        // ---------------- mgb path (scratch overlaid on Klds: 4132B <= 26624B)
        const int b = blockIdx.x - 3072, t = threadIdx.x;
        float* qs   = reinterpret_cast<float*>(Klds);        // [768]
        float* red  = qs + 768;                              // [256]
        float* vals = red + 256;                             // [9]
        qs[t]       = q0[b * 768 + t];
        qs[t + 256] = q0[b * 768 + t + 256];
        qs[t + 512] = q0[b * 768 + t + 512];
        __syncthreads();
        for (int j = 0; j < 9; ++j) {
            float p;
            if (j < 3)
                p = qs[t] * wD[t * 3 + j] + qs[t + 256] * wD[(t + 256) * 3 + j] +
                    qs[t + 512] * wD[(t + 512) * 3 + j];
            else {
                int c = j - 3;
                p = qs[t] * wcen[t * 6 + c] + qs[t + 256] * wcen[(t + 256) * 6 + c] +
                    qs[t + 512] * wcen[(t + 512) * 6 + c];
            }
            red[t] = p;
            __syncthreads();
            for (int off = 128; off > 0; off >>= 1) {
                if (t < off) red[t] += red[t + off];
                __syncthreads();
            }
            if (t == 0) {
                float bias = (j < 3) ? bD[j] : bcen[j - 3];
                vals[j] = 1.f / (1.f + __expf(-(red[0] + bias)));
            }
            __syncthreads();
        }
        if (t < 6) cen_out[b * 6 + t] = vals[3 + t];

        float e3[3] = {0.f, 0.f, 0.f};
        if (t < 196) {
            float gx = 8.f + 16.f * (float)(t / 14);   // GRIDS x-major
            float gy = 8.f + 16.f * (float)(t % 14);
#pragma unroll
            for (int j = 0; j < 3; ++j) {
                float sig = 112.f * vals[j];
                float cx = vals[3 + 2 * j] * 223.f;
                float cy = vals[3 + 2 * j + 1] * 223.f;
                float dx = cx - gx, dy = cy - gy;
                e3[j] = __expf(-(dx * dx + dy * dy) / (2.f * sig * sig));
            }
        }
        float js[3];
        for (int j = 0; j < 3; ++j) {
            red[t] = e3[j];
            __syncthreads();
            for (int off = 128; off > 0; off >>= 1) {
                if (t < off) red[t] += red[t + off];
                __syncthreads();
            }
            js[j] = red[0];
            __syncthreads();
        }
        if (t < 196) {
            float m = (e3[0] / js[0] + e3[1] / js[1] + e3[2] / js[2]) * (1.f / 3.f);
            mgb[(size_t)b * 198 + 2 + t] = m;
        }
        if (t < 2) mgb[(size_t)b * 198 + t] = 1.f;
        return;
    }

    // ---------------- attn path (unchanged)
    const int bh = blockIdx.x;
    const int b = bh / 12, h = bh % 12;
    const __bf16* Qp = qb + (size_t)bh * NN * 64;
    const __bf16* Kp = kb + (size_t)bh * NN * 64;
    const __bf16* Vp = vb + (size_t)bh * NN * 64;
    const int tid = threadIdx.x, lane = tid & 63, wid = tid >> 6;
    const int lr = lane & 15, lg = lane >> 4;

    {
        const int rsub = wid * 8 + (lane >> 3);            // 0..31 within issue
        const int sl   = ((lane & 7) ^ ((lane >> 3) & 7)) * 8;
#pragma unroll
        for (int i = 0; i < 7; ++i) {
            if (i < 6 || wid < 2) {
                int row = i * 32 + rsub;
                int rowc = row < 198 ? row : 197;
                GLOAD_LDS16(Kp + (size_t)rowc * 64 + sl,
                            Klds + (size_t)i * 2048 + wid * 512);
            }
        }
    }

    for (int i = tid; i < 104 * 8; i += 256) {
        int key2 = (i >> 3) * 2, d0 = (i & 7) << 3;
        int kr0 = key2 < 198 ? key2 : 197;
        int kr1 = key2 + 1 < 198 ? key2 + 1 : 197;
        bf16x8 h0 = *reinterpret_cast<const bf16x8*>(Vp + kr0 * 64 + d0);
        bf16x8 h1 = *reinterpret_cast<const bf16x8*>(Vp + kr1 * 64 + d0);
#pragma unroll
        for (int j = 0; j < 8; ++j) {
            union { __bf16 hh[2]; unsigned u; } pk;
            pk.hh[0] = h0[j]; pk.hh[1] = h1[j];
            *reinterpret_cast<unsigned*>(&Vt[d0 + j][key2]) = pk.u;
        }
    }
    __syncthreads();   // drains vmcnt (K stage) + lgkm (V writes)

    for (int ch = wid; ch < 13; ch += 4) {
        int n0 = ch * 16;
        int qrow = n0 + lr; if (qrow > 197) qrow = 197;
        bf16x8 qf0 = *reinterpret_cast<const bf16x8*>(Qp + qrow * 64 + lg * 8);
        bf16x8 qf1 = *reinterpret_cast<const bf16x8*>(Qp + qrow * 64 + 32 + lg * 8);
        f32x4 sa[13];
#pragma unroll
        for (int t2 = 0; t2 < 13; ++t2) {
            int krow = t2 * 16 + lr;                       // <= 207, in Klds
            const int kx = lr & 7;                         // krow & 7
            bf16x8 kf0 = *reinterpret_cast<const bf16x8*>(
                Klds + krow * 64 + ((lg ^ kx) * 8));
            bf16x8 kf1 = *reinterpret_cast<const bf16x8*>(
                Klds + krow * 64 + (((4 + lg) ^ kx) * 8));
            f32x4 a = (f32x4){0.f, 0.f, 0.f, 0.f};
            a = MFMA16(kf0, qf0, a);
            a = MFMA16(kf1, qf1, a);
            sa[t2] = a;
        }
        float rmax = -1e30f;
#pragma unroll
        for (int t2 = 0; t2 < 13; ++t2)
#pragma unroll
            for (int r = 0; r < 4; ++r) {
                int key = t2 * 16 + lg * 4 + r;
                float vv = (key < 198) ? sa[t2][r] * 0.125f : -1e30f;
                sa[t2][r] = vv;
                rmax = fmaxf(rmax, vv);
            }
        rmax = fmaxf(rmax, __shfl_xor(rmax, 16));
        rmax = fmaxf(rmax, __shfl_xor(rmax, 32));
        float rsum = 0.f;
#pragma unroll
        for (int t2 = 0; t2 < 13; ++t2)
#pragma unroll
            for (int r = 0; r < 4; ++r) {
                float e = __expf(sa[t2][r] - rmax);
                sa[t2][r] = e;
                rsum += e;
            }
        rsum += __shfl_xor(rsum, 16);
        rsum += __shfl_xor(rsum, 32);
        float inv = 1.f / rsum;

        if (ch == 0 && lr == 0) {
#pragma unroll
            for (int t2 = 0; t2 < 13; ++t2)
#pragma unroll
                for (int r = 0; r < 4; ++r) {
                    int key = t2 * 16 + lg * 4 + r;
                    if (key < 198) p0[(size_t)bh * 198 + key] = sa[t2][r] * inv;
                }
        }
#pragma unroll
        for (int t2 = 0; t2 < 13; ++t2) {
            bf16x4 pk;
#pragma unroll
            for (int r = 0; r < 4; ++r) pk[r] = (__bf16)(sa[t2][r] * inv);
            *reinterpret_cast<bf16x4*>(&Plds[wid][lr][t2 * 16 + lg * 4]) = pk;
        }
        asm volatile("s_waitcnt lgkmcnt(0)" ::: "memory");

        f32x4 o[4];
#pragma unroll
        for (int mt = 0; mt < 4; ++mt) o[mt] = (f32x4){0.f, 0.f, 0.f, 0.f};
#pragma unroll
        for (int ks = 0; ks < 7; ++ks) {
            int kbase = ks * 32 + lg * 8;
            bf16x8 pf;
            if (kbase < 208)
                pf = *reinterpret_cast<const bf16x8*>(&Plds[wid][lr][kbase]);
            else {
#pragma unroll
                for (int j = 0; j < 8; ++j) pf[j] = (__bf16)0.f;
            }
#pragma unroll
            for (int mt = 0; mt < 4; ++mt) {
                bf16x8 vf;
                if (kbase < 208)
                    vf = *reinterpret_cast<const bf16x8*>(&Vt[mt * 16 + lr][kbase]);
                else {
#pragma unroll
                    for (int j = 0; j < 8; ++j) vf[j] = (__bf16)0.f;
                }
                o[mt] = MFMA16(vf, pf, o[mt]);
            }
        }
        int qg = n0 + lr;
        if (qg < 198) {
            __bf16* dst = outp + ((size_t)b * 198 + qg) * 768 + h * 64;
#pragma unroll
            for (int mt = 0; mt < 4; ++mt) {
                bf16x4 pk;
#pragma unroll
                for (int r = 0; r < 4; ++r) pk[r] = (__bf16)o[mt][r];
                *reinterpret_cast<bf16x4*>(dst + mt * 16 + lg * 4) = pk;
            }
        }
    }
}

// ---------------------------------------------------------------------------
// CLS-row reweighting (masked_scatter flat-order semantics) — unchanged.
// ---------------------------------------------------------------------------
__global__ __launch_bounds__(64) void reweight_kernel(
    const float* __restrict__ p0, const float* __restrict__ mgb,
    const __bf16* __restrict__ vb, float* __restrict__ attn_out,
    __bf16* __restrict__ outp) {
    const int t = blockIdx.x;          // b*12 + h
    const int b = t / 12, h = t % 12;
    const int h2 = t >> 8, b2 = t & 255;
    const int lane = threadIdx.x;
    __shared__ float nr[198];
    const float* pr = p0 + (size_t)(b2 * 12 + h2) * 198;
    const float* mr = mgb + (size_t)b2 * 198;
    float w[4];
    float ssum = 0.f;
#pragma unroll
    for (int i = 0; i < 4; ++i) {
        int n = lane + 64 * i;
        float xv = (n < 198) ? pr[n] * mr[n] : 0.f;
        w[i] = xv;
        ssum += xv;
    }
#pragma unroll
    for (int m = 1; m < 64; m <<= 1) ssum += __shfl_xor(ssum, m);
    float inv = 1.f / ssum;
#pragma unroll
    for (int i = 0; i < 4; ++i) {
        int n = lane + 64 * i;
        if (n < 198) {
            float xv = w[i] * inv;
            nr[n] = xv;
            attn_out[(size_t)t * 198 + n] = xv;
        }
    }
    __syncthreads();
    const __bf16* vp = vb + (size_t)t * 198 * 64;
    float acc = 0.f;
    for (int n = 0; n < 198; ++n) acc += nr[n] * (float)vp[n * 64 + lane];
    outp[((size_t)b * 198) * 768 + h * 64 + lane] = (__bf16)acc;
}

// ---------------------------------------------------------------------------
// GEMM2 v8 (best measured): 128x128, 4 waves, 3 blocks/CU, BK=32 dbuf,
// counted vmcnt(4).
// ---------------------------------------------------------------------------
__global__ __launch_bounds__(256, 3) void gemm_proj_v8(
    const __bf16* __restrict__ A, const __bf16* __restrict__ wT,
    const float* __restrict__ bias, float* __restrict__ out) {
    __shared__ __bf16 As[2][128 * 32];
    __shared__ __bf16 Bs[2][128 * 32];
    const int bid = blockIdx.x;
    const int wg  = (bid & 7) * 297 + (bid >> 3);   // bijective: 2376 = 8*297
    const int brow = (wg / 6) * 128;
    const int bcol = (wg % 6) * 128;
    const int tid = threadIdx.x, lane = tid & 63, wid = tid >> 6;
    const int wm = wid >> 1, wn = wid & 1;
    const int lr = lane & 15, lg = lane >> 4;

    const int srow = tid >> 2;
    const int sslot = (tid & 3) ^ ((tid >> 3) & 3);
    const __bf16* aSrc = A  + (size_t)(brow + srow) * 768 + sslot * 8;
    const __bf16* bSrc = wT + (size_t)(bcol + srow) * 768 + sslot * 8;
    const int rkey = (lr >> 1) & 3;

    f32x4 acc[4][4] = {};

#define STAGE_P6(buf, kk0)                                                    \
    {                                                                         \
        __bf16* aD = &As[buf][wid * 512];                                     \
        __bf16* bD = &Bs[buf][wid * 512];                                     \
        GLOAD_LDS16(aSrc + (kk0), aD);                                        \
        GLOAD_LDS16(bSrc + (kk0), bD);                                        \
        GLOAD_LDS16(aSrc + (size_t)64 * 768 + (kk0), aD + 2048);              \
        GLOAD_LDS16(bSrc + (size_t)64 * 768 + (kk0), bD + 2048);              \
    }

#define COMPUTE_P6(buf)                                                       \
    {                                                                         \
        const __bf16* Ab = As[buf];                                           \
        const __bf16* Bb = Bs[buf];                                           \
        bf16x8 af[4], bfv[4];                                                 \
        _Pragma("unroll")                                                     \
        for (int nt = 0; nt < 4; ++nt)                                        \
            bfv[nt] = *reinterpret_cast<const bf16x8*>(                       \
                Bb + (wn * 64 + nt * 16 + lr) * 32 + ((lg ^ rkey) * 8));      \
        _Pragma("unroll")                                                     \
        for (int mt = 0; mt < 4; ++mt)                                        \
            af[mt] = *reinterpret_cast<const bf16x8*>(                        \
                Ab + (wm * 64 + mt * 16 + lr) * 32 + ((lg ^ rkey) * 8));      \
        __builtin_amdgcn_s_setprio(1);                                        \
        _Pragma("unroll")                                                     \
        for (int mt = 0; mt < 4; ++mt)                                        \
            _Pragma("unroll")                                                 \
            for (int nt = 0; nt < 4; ++nt)                                    \
                acc[mt][nt] = MFMA16(af[mt], bfv[nt], acc[mt][nt]);           \
        __builtin_amdgcn_s_setprio(0);                                        \
    }

    STAGE_P6(0, 0);
    STAGE_P6(1, 32);
    for (int tau = 0; tau < 24; ++tau) {
        if (tau == 23) asm volatile("s_waitcnt vmcnt(0)" ::: "memory");
        else           asm volatile("s_waitcnt vmcnt(4)" ::: "memory");
        __builtin_amdgcn_s_barrier();
        __builtin_amdgcn_sched_barrier(0);
        COMPUTE_P6(tau & 1);
        __builtin_amdgcn_sched_barrier(0);
        __builtin_amdgcn_s_barrier();
        __builtin_amdgcn_sched_barrier(0);
        if (tau < 22) STAGE_P6(tau & 1, (tau + 2) * 32);
    }
#undef STAGE_P6
#undef COMPUTE_P6

#pragma unroll
    for (int mt = 0; mt < 4; ++mt) {
#pragma unroll
        for (int nt = 0; nt < 4; ++nt) {
            int gcol = bcol + wn * 64 + nt * 16 + lr;
            float bv = bias[gcol];
#pragma unroll
            for (int r = 0; r < 4; ++r) {
                int grow = brow + wm * 64 + mt * 16 + lg * 4 + r;
                out[(size_t)grow * 768 + gcol] = acc[mt][nt][r] + bv;
            }
        }
    }
}

// ---------------------------------------------------------------------------
extern "C" void kernel_launch(void* const* d_in, const int* in_sizes, int n_in,
                              void* d_out, int out_size, void* d_ws, size_t ws_size,
                              hipStream_t stream) {
    const float* x      = (const float*)d_in[0];
    const float* w_qkv  = (const float*)d_in[1];
    const float* w_proj = (const float*)d_in[2];
    const float* b_proj = (const float*)d_in[3];
    const float* w_D    = (const float*)d_in[4];
    const float* b_D    = (const float*)d_in[5];
    const float* w_cen  = (const float*)d_in[6];
    const float* b_cen  = (const float*)d_in[7];

    float* out      = (float*)d_out;
    float* cen_out  = out;                    // [256,3,2]  = 1536
    float* attn_out = out + 1536;             // [256,12,198] = 608256
    float* proj_out = out + 1536 + 608256;    // [256,198,768]

    char* ws = (char*)d_ws;
    size_t off = 0;
    auto carve = [&](size_t bytes) {
        void* p = ws + off;
        off += (bytes + 255) & ~(size_t)255;
        return p;
    };
    __bf16* wqkvT  = (__bf16*)carve((size_t)2304 * 768 * 2);
    __bf16* wprojT = (__bf16*)carve((size_t)768 * 768 * 2);
    __bf16* qb     = (__bf16*)carve((size_t)3072 * 198 * 64 * 2);
    __bf16* kb     = (__bf16*)carve((size_t)3072 * 198 * 64 * 2);
    __bf16* vb     = (__bf16*)carve((size_t)3072 * 198 * 64 * 2);
    __bf16* outp   = (__bf16*)carve((size_t)50688 * 768 * 2);
    float*  q0     = (float*)carve((size_t)256 * 768 * 4);
    float*  mgb    = (float*)carve((size_t)256 * 198 * 4);
    float*  p0     = (float*)carve((size_t)3072 * 198 * 4);

    // xb aliases outp: xb is dead before attn_mgb_kernel writes outp
    __bf16* xb = outp;

    prep_kernel<<<2048 + 1728 + 576, 256, 0, stream>>>(x, xb, w_qkv, wqkvT, w_proj, wprojT);
    gemm_qkv_v7<<<1782, 512, 0, stream>>>(xb, wqkvT, qb, kb, vb, q0);
    attn_mgb_kernel<<<3072 + 256, 256, 0, stream>>>(qb, kb, vb, p0, outp,
                                                    q0, w_D, b_D, w_cen, b_cen,
                                                    cen_out, mgb);
    reweight_kernel<<<3072, 64, 0, stream>>>(p0, mgb, vb, attn_out, outp);
    gemm_proj_v8<<<2376, 256, 0, stream>>>(outp, wprojT, b_proj, proj_out);
}